// Round 3
// baseline (744.174 us; speedup 1.0000x reference)
//
#include <hip/hip_runtime.h>
#include <math.h>

// RVQECell on MI355X.
// State: [B=32][2^19] fp32. Lane l <-> state bit (18-l). inout = bits 13..18,
// work = bits 1..12, ancilla = bit 0 (spectator).
//
// R3: locality-first main_kernel. 512 blocks x 512 threads, fully co-resident
// (2 blocks/CU). Each block: one vt (table slice set), 2 LDS state slots x 2
// iterations = 4 batches, full barrier lockstep (R1 structure) so the per-XCD
// concurrent table working set stays ~384 KiB (L2-resident; tables hit HBM
// once per XCD ~ 48 MiB total). probs fused into out_kernel via LDS transpose
// + atomicAdd (probs zeroed by main block 0; stream order guarantees safety).

#define BIAS_F 1.57079632679489662f

// ---- LDS bank swizzle: fold bits 7..5 into 4..2 (keeps float4 contiguity) ----
__device__ __forceinline__ int SW(int i) { return i ^ ((i >> 3) & 0x1C); }
__device__ __forceinline__ float4 ldsld4(const float* st, int i) {
    return *(const float4*)&st[SW(i)];
}
__device__ __forceinline__ void ldsst4(float* st, int i, float4 v) {
    *(float4*)&st[SW(i)] = v;
}
#define T4(t, i) (*(const float4*)&(t)[i])

// rotation on pairs (A.k, B.k); e = (c01,s01,c23,s23); .x/.y share angle (bit0)
__device__ __forceinline__ void rot4(float4& A, float4& B, float4 e) {
    float ax = A.x, ay = A.y, az = A.z, aw = A.w;
    A.x = e.x * ax - e.y * B.x;  B.x = e.y * ax + e.x * B.x;
    A.y = e.x * ay - e.y * B.y;  B.y = e.y * ay + e.x * B.y;
    A.z = e.z * az - e.w * B.z;  B.z = e.w * az + e.z * B.z;
    A.w = e.z * aw - e.w * B.w;  B.w = e.w * aw + e.z * B.w;
}
// rotation within a quad: pairs (x,z),(y,w)  (target = amp bit 1)
__device__ __forceinline__ void rotq(float4& P, float c, float s) {
    float px = P.x, py = P.y;
    P.x = c * px - s * P.z;  P.z = s * px + c * P.z;
    P.y = c * py - s * P.w;  P.w = s * py + c * P.w;
}

// ============================ K1: tables ============================
__global__ __launch_bounds__(256) void tables_kernel(
    const float* __restrict__ w_in1, const float* __restrict__ w_in2,
    const float* __restrict__ w_k1,  const float* __restrict__ w_k2,
    const float* __restrict__ w_out1, const float* __restrict__ w_out2,
    float2* __restrict__ tab)
{
    const int n = blockIdx.y;
    const int hi = blockIdx.x;       // x bits 16..8
    const int tid = threadIdx.x;     // x bits 7..0
    const float* th1;
    const float* th2;
    if (n < 12)      { th1 = w_in1 + n * 17;         th2 = w_in2 + n * 289; }
    else if (n < 48) { th1 = w_k1 + (n - 12) * 17;   th2 = w_k2 + (n - 12) * 289; }
    else             { th1 = w_out1 + (n - 48) * 17; th2 = w_out2 + (n - 48) * 289; }

    float bu[9], bt[8];
#pragma unroll
    for (int i = 0; i < 9; ++i) bu[i] = (float)((hi >> (8 - i)) & 1);
#pragma unroll
    for (int j = 0; j < 8; ++j) bt[j] = (float)((tid >> (7 - j)) & 1);

    float phi = BIAS_F;
#pragma unroll
    for (int i = 0; i < 9; ++i) {
        float acc = th1[i];
#pragma unroll
        for (int j = i + 1; j < 9; ++j) acc += bu[j] * th2[i * 17 + j];
#pragma unroll
        for (int j = 0; j < 8; ++j)     acc += bt[j] * th2[i * 17 + 9 + j];
        phi += bu[i] * acc;
    }
#pragma unroll
    for (int a = 0; a < 8; ++a) {
        float acc = th1[9 + a];
#pragma unroll
        for (int b2 = a + 1; b2 < 8; ++b2) acc += bt[b2] * th2[(9 + a) * 17 + 9 + b2];
        phi += bt[a] * acc;
    }
    float sp, cp;
    sincosf(phi, &sp, &cp);
    float c2 = cp * cp, s2 = sp * sp;
    float d = c2 * c2 + s2 * s2;           // >= 0.25 always
    float r = rsqrtf(d);
    r = r * (1.5f - 0.5f * d * r * r);     // one Newton step
    tab[(size_t)n * 131072 + ((hi << 8) | tid)] = make_float2(c2 * r, s2 * r);
}

// ============================ K2: main fused ============================
// Generic 3-target pass body (verified in R1/R2). Targets {PA, PA-1, PA-2}.
template <int PA, bool NEUR>
__device__ __forceinline__ void pass_gen(float* st, int i0, int x0,
    const float2* tA, const float2* tB, const float2* tC,
    float cA, float sA, float cB, float sB, float cC, float sC)
{
    const int oa = 1 << PA, ob = oa >> 1, oc = oa >> 2;
    const int dhi = oa >> 2, dlo = oa >> 3;   // table offsets (x-index space)
    float4 Q000 = ldsld4(st, i0),            Q001 = ldsld4(st, i0 + oc);
    float4 Q010 = ldsld4(st, i0 + ob),       Q011 = ldsld4(st, i0 + ob + oc);
    float4 Q100 = ldsld4(st, i0 + oa),       Q101 = ldsld4(st, i0 + oa + oc);
    float4 Q110 = ldsld4(st, i0 + oa + ob),  Q111 = ldsld4(st, i0 + oa + ob + oc);
    if (NEUR) {
        {   // target PA
            float4 e00 = T4(tA, x0), e01 = T4(tA, x0 + dlo),
                   e10 = T4(tA, x0 + dhi), e11 = T4(tA, x0 + dhi + dlo);
            rot4(Q000, Q100, e00); rot4(Q001, Q101, e01);
            rot4(Q010, Q110, e10); rot4(Q011, Q111, e11);
        }
        {   // target PA-1
            float4 e00 = T4(tB, x0), e01 = T4(tB, x0 + dlo),
                   e10 = T4(tB, x0 + dhi), e11 = T4(tB, x0 + dhi + dlo);
            rot4(Q000, Q010, e00); rot4(Q001, Q011, e01);
            rot4(Q100, Q110, e10); rot4(Q101, Q111, e11);
        }
        {   // target PA-2
            float4 e00 = T4(tC, x0), e01 = T4(tC, x0 + dlo),
                   e10 = T4(tC, x0 + dhi), e11 = T4(tC, x0 + dhi + dlo);
            rot4(Q000, Q001, e00); rot4(Q010, Q011, e01);
            rot4(Q100, Q101, e10); rot4(Q110, Q111, e11);
        }
    } else {
        float4 eA = make_float4(cA, sA, cA, sA);
        rot4(Q000, Q100, eA); rot4(Q001, Q101, eA);
        rot4(Q010, Q110, eA); rot4(Q011, Q111, eA);
        float4 eB = make_float4(cB, sB, cB, sB);
        rot4(Q000, Q010, eB); rot4(Q001, Q011, eB);
        rot4(Q100, Q110, eB); rot4(Q101, Q111, eB);
        float4 eC = make_float4(cC, sC, cC, sC);
        rot4(Q000, Q001, eC); rot4(Q010, Q011, eC);
        rot4(Q100, Q101, eC); rot4(Q110, Q111, eC);
    }
    ldsst4(st, i0, Q000);            ldsst4(st, i0 + oc, Q001);
    ldsst4(st, i0 + ob, Q010);       ldsst4(st, i0 + ob + oc, Q011);
    ldsst4(st, i0 + oa, Q100);       ldsst4(st, i0 + oa + oc, Q101);
    ldsst4(st, i0 + oa + ob, Q110);  ldsst4(st, i0 + oa + ob + oc, Q111);
}

// High pass on a slot: st = slot base, t8 = 0..255 (one slot's workers).
template <int PA, bool NEUR>
__device__ __forceinline__ void pass_hi(float* st, int t8,
    const float2* tA, const float2* tB, const float2* tC,
    float cA, float sA, float cB, float sB, float cC, float sC)
{
    const int lowb = PA - 4;
    const int low = t8 & ((1 << lowb) - 1);
    const int high = t8 >> lowb;
    const int i0 = (high << (PA + 1)) | (low << 2);
    const int x0 = (high << (PA - 1)) | (low << 1);
    pass_gen<PA, NEUR>(st, i0, x0, tA, tB, tC, cA, sA, cB, sB, cC, sC);
}

// Low pass on a slot: targets {3,2,1}; 16 consecutive amps per group, 2 groups.
template <bool NEUR>
__device__ __forceinline__ void pass_lo(float* st, int t8,
    const float2* tA, const float2* tB, const float2* tC,
    float cA, float sA, float cB, float sB, float cC, float sC)
{
#pragma unroll
    for (int g = 0; g < 2; ++g) {
        const int h = t8 + (g << 8);   // 0..511
        const int i0 = h << 4;
        float4 P00 = ldsld4(st, i0),     P01 = ldsld4(st, i0 + 4);
        float4 P10 = ldsld4(st, i0 + 8), P11 = ldsld4(st, i0 + 12);
        if (NEUR) {
            const int x0 = h << 2;
            float4 eA0 = T4(tA, x0), eA1 = T4(tA, x0 + 2);
            rot4(P00, P10, eA0); rot4(P01, P11, eA1);          // bit 3
            float4 eB0 = T4(tB, x0), eB1 = T4(tB, x0 + 2);
            rot4(P00, P01, eB0); rot4(P10, P11, eB1);          // bit 2
            float4 c0 = T4(tC, x0), c1 = T4(tC, x0 + 2);       // bit 1 (in-quad)
            rotq(P00, c0.x, c0.y); rotq(P01, c0.z, c0.w);
            rotq(P10, c1.x, c1.y); rotq(P11, c1.z, c1.w);
        } else {
            float4 eA = make_float4(cA, sA, cA, sA);
            rot4(P00, P10, eA); rot4(P01, P11, eA);
            float4 eB = make_float4(cB, sB, cB, sB);
            rot4(P00, P01, eB); rot4(P10, P11, eB);
            rotq(P00, cC, sC); rotq(P01, cC, sC);
            rotq(P10, cC, sC); rotq(P11, cC, sC);
        }
        ldsst4(st, i0, P00);     ldsst4(st, i0 + 4, P01);
        ldsst4(st, i0 + 8, P10); ldsst4(st, i0 + 12, P11);
    }
}

__global__ __launch_bounds__(512, 4) void main_kernel(
    const float* __restrict__ batch, const float* __restrict__ w_u,
    const int* __restrict__ inputs, const float2* __restrict__ tab,
    float* __restrict__ psi, float* __restrict__ probs)
{
    __shared__ __align__(16) float lds[2][8192];   // 64 KiB: 2 state slots
    const int tid = threadIdx.x;
    const int slot = tid >> 8, t8 = tid & 255;
    const int blk = blockIdx.x;
    // blk&7 = XCD (round-robin heuristic). vt = (xcd<<3)|vtl -> each XCD owns
    // 8 vt slice-sets; all 8 same-vt blocks land on the same XCD.
    const int xcd = blk & 7, vtl = (blk >> 3) & 7, grp = blk >> 6;
    const int vt = (xcd << 3) | vtl;
    float* st = lds[slot];

    if (blk == 0) {   // zero probs for out_kernel atomics (runs before out)
        float4 z = make_float4(0.f, 0.f, 0.f, 0.f);
        *(float4*)&probs[tid * 4] = z;             // 512*4 = 2048 floats
    }

    const float2* tb = tab + (vt << 11);
#define TN(j) (tb + (size_t)(j) * 131072)
#define BAR __syncthreads()

#pragma unroll 1
    for (int iter = 0; iter < 2; ++iter) {
        const int b = (grp << 2) | (iter << 1) | slot;
        int fb = 0;
#pragma unroll
        for (int i = 0; i < 6; ++i) fb |= (inputs[b * 6 + i] & 1) << (5 - i);
        const int u = vt ^ fb;            // physical block (bitflips folded)

        const float* src = batch + ((size_t)b << 19) + ((size_t)u << 13);
#pragma unroll
        for (int k = 0; k < 8; ++k) {
            int i4 = (k * 256 + t8) * 4;
            float4 v = *(const float4*)&src[i4];
            *(float4*)&st[SW(i4)] = v;
        }
        BAR;
        // ---- input layer (neurons 0..11, target bit 12-j) ----
        pass_hi<12, true>(st, t8, TN(0), TN(1), TN(2), 0,0,0,0,0,0);  BAR;
        pass_hi<9,  true>(st, t8, TN(3), TN(4), TN(5), 0,0,0,0,0,0);  BAR;
        pass_hi<6,  true>(st, t8, TN(6), TN(7), TN(8), 0,0,0,0,0,0);  BAR;
        pass_lo<true>(st, t8, TN(9), TN(10), TN(11), 0,0,0,0,0,0);    BAR;

#pragma unroll 1
        for (int st2 = 0; st2 < 3; ++st2) {
            const float* wu = w_u + st2 * 12;
            float c0, s0, c1, s1, c2, s2;
            sincosf(wu[0], &s0, &c0); sincosf(wu[1], &s1, &c1); sincosf(wu[2], &s2, &c2);
            pass_hi<12, false>(st, t8, 0,0,0, c0,s0, c1,s1, c2,s2);   BAR;
            sincosf(wu[3], &s0, &c0); sincosf(wu[4], &s1, &c1); sincosf(wu[5], &s2, &c2);
            pass_hi<9, false>(st, t8, 0,0,0, c0,s0, c1,s1, c2,s2);    BAR;
            sincosf(wu[6], &s0, &c0); sincosf(wu[7], &s1, &c1); sincosf(wu[8], &s2, &c2);
            pass_hi<6, false>(st, t8, 0,0,0, c0,s0, c1,s1, c2,s2);    BAR;
            sincosf(wu[9], &s0, &c0); sincosf(wu[10], &s1, &c1); sincosf(wu[11], &s2, &c2);
            pass_lo<false>(st, t8, 0,0,0, c0,s0, c1,s1, c2,s2);       BAR;

            const int nb = 12 + st2 * 12;
            pass_hi<12, true>(st, t8, TN(nb+0), TN(nb+1), TN(nb+2), 0,0,0,0,0,0); BAR;
            pass_hi<9,  true>(st, t8, TN(nb+3), TN(nb+4), TN(nb+5), 0,0,0,0,0,0); BAR;
            pass_hi<6,  true>(st, t8, TN(nb+6), TN(nb+7), TN(nb+8), 0,0,0,0,0,0); BAR;
            pass_lo<true>(st, t8, TN(nb+9), TN(nb+10), TN(nb+11), 0,0,0,0,0,0);   BAR;
        }

        float* dst = psi + ((size_t)b << 19) + ((size_t)u << 13);
#pragma unroll
        for (int k = 0; k < 8; ++k) {
            int i4 = (k * 256 + t8) * 4;
            *(float4*)&dst[i4] = *(const float4*)&st[SW(i4)];
        }
        BAR;   // LDS reuse guard for next iteration
    }
#undef TN
#undef BAR
}

// ============================ K3: output layer + probs ============================
// One thread per low-13-bit column; 64 inout amps in registers; after writing
// psi, reduce |amp|^2 across the block via XOR-swizzled LDS transpose and
// atomicAdd into probs[b*64+k].
__global__ __launch_bounds__(256, 2) void out_kernel(
    const float2* __restrict__ tab, float* __restrict__ psi,
    float* __restrict__ probs)
{
    __shared__ float ts[16384];   // 64 KiB transpose buffer
    const int tid = threadIdx.x;
    const int b = blockIdx.x >> 5;
    const int col = ((blockIdx.x & 31) << 8) | tid;
    float* base = psi + ((size_t)b << 19) + col;
    float a[64];
#pragma unroll
    for (int k = 0; k < 64; ++k) a[k] = base[(size_t)k << 13];
    const int w12 = col >> 1;
#pragma unroll
    for (int j = 0; j < 6; ++j) {
        const float2* tj = tab + (size_t)(48 + j) * 131072 + w12;
        const int q = 5 - j;
#pragma unroll
        for (int m = 0; m < 32; ++m) {
            int k0 = ((m >> q) << (q + 1)) | (m & ((1 << q) - 1));
            int k1 = k0 | (1 << q);
            float2 e = tj[(size_t)m << 12];
            float a0 = a[k0], a1 = a[k1];
            a[k0] = e.x * a0 - e.y * a1;
            a[k1] = e.y * a0 + e.x * a1;
        }
    }
#pragma unroll
    for (int k = 0; k < 64; ++k) base[(size_t)k << 13] = a[k];

    // ---- probs reduction: ts[r*64 + (k ^ (r&63))] = a_r[k]^2 ----
    const int jx = tid & 63;
#pragma unroll
    for (int k = 0; k < 64; ++k) ts[tid * 64 + (k ^ jx)] = a[k] * a[k];
    __syncthreads();
    const int k = tid & 63, seg = tid >> 6;
    float p = 0.f;
#pragma unroll
    for (int j = 0; j < 64; ++j) p += ts[(seg * 64 + j) * 64 + (k ^ j)];
    atomicAdd(&probs[b * 64 + k], p);
}

// ============================ launch ============================
extern "C" void kernel_launch(void* const* d_in, const int* in_sizes, int n_in,
                              void* d_out, int out_size, void* d_ws, size_t ws_size,
                              hipStream_t stream)
{
    const float* batch  = (const float*)d_in[0];
    const float* w_in1  = (const float*)d_in[1];
    const float* w_in2  = (const float*)d_in[2];
    const float* w_u    = (const float*)d_in[3];
    const float* w_k1   = (const float*)d_in[4];
    const float* w_k2   = (const float*)d_in[5];
    const float* w_out1 = (const float*)d_in[6];
    const float* w_out2 = (const float*)d_in[7];
    const int*   inputs = (const int*)d_in[8];
    float* probs = (float*)d_out;
    float* psi   = (float*)d_out + 2048;      // 32*64 probs, then 32*2^19 psi
    float2* tab  = (float2*)d_ws;             // 54 * 131072 * 8B = 54 MiB

    tables_kernel<<<dim3(512, 54), 256, 0, stream>>>(w_in1, w_in2, w_k1, w_k2,
                                                     w_out1, w_out2, tab);
    main_kernel<<<512, 512, 0, stream>>>(batch, w_u, inputs, tab, psi, probs);
    out_kernel<<<1024, 256, 0, stream>>>(tab, psi, probs);
}

// Round 5
// 392.451 us; speedup vs baseline: 1.8962x; 1.8962x over previous
//
#include <hip/hip_runtime.h>
#include <math.h>

// RVQECell on MI355X.
// State: [B=32][2^19] fp32. Lane l <-> state bit (18-l). inout = bits 13..18,
// work = bits 1..12, ancilla = bit 0 (spectator).
//
// R5 = R4 with the nontemporal builtin fixed (needs a native ext_vector_type,
// not HIP's float4 class). Strategy evidence (R1/R3): main_kernel pegged at
// ~2.7 TB/s L2-fill BW regardless of structure -> reduce missed bytes:
//  (a) tables packed to 4 B/entry: store +-min(cos a, sin a); decode with
//      sqrt(1-v^2) (error ~2^-24).
//  (b) each block holds 2 batch states in LDS (64 KiB); same thread loads
//      packed table regs once, applies to both slots (register reuse).
//      Table bytes/batch: 768 KiB -> 192 KiB.
//  (c) nontemporal loads/stores for the once-touched state streams.

#define BIAS_F 1.57079632679489662f

typedef float v4f __attribute__((ext_vector_type(4)));

__device__ __forceinline__ float4 ntload4(const float* p) {
    v4f v = __builtin_nontemporal_load((const v4f*)p);
    return make_float4(v.x, v.y, v.z, v.w);
}
__device__ __forceinline__ void ntstore4(float* p, float4 f) {
    v4f v = {f.x, f.y, f.z, f.w};
    __builtin_nontemporal_store(v, (v4f*)p);
}

// ---- LDS bank swizzle: fold bits 7..5 into 4..2 (keeps float4 contiguity) ----
__device__ __forceinline__ int SW(int i) { return i ^ ((i >> 3) & 0x1C); }
__device__ __forceinline__ float4 ldsld4(const float* st, int i) {
    return *(const float4*)&st[SW(i)];
}
__device__ __forceinline__ void ldsst4(float* st, int i, float4 v) {
    *(float4*)&st[SW(i)] = v;
}

// decode packed entry: v = c if c<=s (v>=0) else -s
__device__ __forceinline__ float2 dec(float v) {
    float t = sqrtf(fmaf(-v, v, 1.0f));
    float c = v >= 0.f ? v : t;
    float s = v >= 0.f ? t : -v;
    return make_float2(c, s);
}
__device__ __forceinline__ float4 dec4(float2 g) {
    float2 u = dec(g.x), w = dec(g.y);
    return make_float4(u.x, u.y, w.x, w.y);
}
#define LD2(p) (*(const float2*)(p))
#define LD4(p) (*(const float4*)(p))

// rotation on pairs (A.k, B.k); e = (c01,s01,c23,s23); .x/.y share angle (bit0)
__device__ __forceinline__ void rot4(float4& A, float4& B, float4 e) {
    float ax = A.x, ay = A.y, az = A.z, aw = A.w;
    A.x = e.x * ax - e.y * B.x;  B.x = e.y * ax + e.x * B.x;
    A.y = e.x * ay - e.y * B.y;  B.y = e.y * ay + e.x * B.y;
    A.z = e.z * az - e.w * B.z;  B.z = e.w * az + e.z * B.z;
    A.w = e.z * aw - e.w * B.w;  B.w = e.w * aw + e.z * B.w;
}
// rotation within a quad: pairs (x,z),(y,w)  (target = amp bit 1)
__device__ __forceinline__ void rotq(float4& P, float c, float s) {
    float px = P.x, py = P.y;
    P.x = c * px - s * P.z;  P.z = s * px + c * P.z;
    P.y = c * py - s * P.w;  P.w = s * py + c * P.w;
}

// ============================ K1: tables ============================
__global__ __launch_bounds__(256) void tables_kernel(
    const float* __restrict__ w_in1, const float* __restrict__ w_in2,
    const float* __restrict__ w_k1,  const float* __restrict__ w_k2,
    const float* __restrict__ w_out1, const float* __restrict__ w_out2,
    float* __restrict__ tab)
{
    const int n = blockIdx.y;
    const int hi = blockIdx.x;       // x bits 16..8
    const int tid = threadIdx.x;     // x bits 7..0
    const float* th1;
    const float* th2;
    if (n < 12)      { th1 = w_in1 + n * 17;         th2 = w_in2 + n * 289; }
    else if (n < 48) { th1 = w_k1 + (n - 12) * 17;   th2 = w_k2 + (n - 12) * 289; }
    else             { th1 = w_out1 + (n - 48) * 17; th2 = w_out2 + (n - 48) * 289; }

    float bu[9], bt[8];
#pragma unroll
    for (int i = 0; i < 9; ++i) bu[i] = (float)((hi >> (8 - i)) & 1);
#pragma unroll
    for (int j = 0; j < 8; ++j) bt[j] = (float)((tid >> (7 - j)) & 1);

    float phi = BIAS_F;
#pragma unroll
    for (int i = 0; i < 9; ++i) {
        float acc = th1[i];
#pragma unroll
        for (int j = i + 1; j < 9; ++j) acc += bu[j] * th2[i * 17 + j];
#pragma unroll
        for (int j = 0; j < 8; ++j)     acc += bt[j] * th2[i * 17 + 9 + j];
        phi += bu[i] * acc;
    }
#pragma unroll
    for (int a = 0; a < 8; ++a) {
        float acc = th1[9 + a];
#pragma unroll
        for (int b2 = a + 1; b2 < 8; ++b2) acc += bt[b2] * th2[(9 + a) * 17 + 9 + b2];
        phi += bt[a] * acc;
    }
    float sp, cp;
    sincosf(phi, &sp, &cp);
    float c2 = cp * cp, s2 = sp * sp;
    float d = c2 * c2 + s2 * s2;           // >= 0.25 always
    float r = rsqrtf(d);
    r = r * (1.5f - 0.5f * d * r * r);     // one Newton step
    float ca = c2 * r, sa = s2 * r;        // cos a, sin a in [0,1]
    tab[(size_t)n * 131072 + ((hi << 8) | tid)] = (ca <= sa) ? ca : -sa;
}

// ============================ K2: main fused ============================
// High pass, targets {PA,PA-1,PA-2}; packed table regs reused for both slots.
template <int PA, bool NEUR>
__device__ __forceinline__ void pass_hi2(float* l0, float* l1, int t8,
    const float* tA, const float* tB, const float* tC,
    float cA, float sA, float cB, float sB, float cC, float sC)
{
    const int lowb = PA - 4;
    const int low = t8 & ((1 << lowb) - 1);
    const int high = t8 >> lowb;
    const int i0 = (high << (PA + 1)) | (low << 2);
    const int x0 = (high << (PA - 1)) | (low << 1);
    const int oa = 1 << PA, ob = oa >> 1, oc = oa >> 2;
    const int dhi = oa >> 2, dlo = oa >> 3;
    float2 pa0, pa1, pa2, pa3, pb0, pb1, pb2, pb3, pc0, pc1, pc2, pc3;
    if (NEUR) {
        pa0 = LD2(&tA[x0]);       pa1 = LD2(&tA[x0 + dlo]);
        pa2 = LD2(&tA[x0 + dhi]); pa3 = LD2(&tA[x0 + dhi + dlo]);
        pb0 = LD2(&tB[x0]);       pb1 = LD2(&tB[x0 + dlo]);
        pb2 = LD2(&tB[x0 + dhi]); pb3 = LD2(&tB[x0 + dhi + dlo]);
        pc0 = LD2(&tC[x0]);       pc1 = LD2(&tC[x0 + dlo]);
        pc2 = LD2(&tC[x0 + dhi]); pc3 = LD2(&tC[x0 + dhi + dlo]);
    }
#pragma unroll
    for (int s = 0; s < 2; ++s) {
        float* sl = (s == 0) ? l0 : l1;
        float4 Q000 = ldsld4(sl, i0),            Q001 = ldsld4(sl, i0 + oc);
        float4 Q010 = ldsld4(sl, i0 + ob),       Q011 = ldsld4(sl, i0 + ob + oc);
        float4 Q100 = ldsld4(sl, i0 + oa),       Q101 = ldsld4(sl, i0 + oa + oc);
        float4 Q110 = ldsld4(sl, i0 + oa + ob),  Q111 = ldsld4(sl, i0 + oa + ob + oc);
        if (NEUR) {
            {   // target PA
                float4 e00 = dec4(pa0), e01 = dec4(pa1), e10 = dec4(pa2), e11 = dec4(pa3);
                rot4(Q000, Q100, e00); rot4(Q001, Q101, e01);
                rot4(Q010, Q110, e10); rot4(Q011, Q111, e11);
            }
            {   // target PA-1
                float4 e00 = dec4(pb0), e01 = dec4(pb1), e10 = dec4(pb2), e11 = dec4(pb3);
                rot4(Q000, Q010, e00); rot4(Q001, Q011, e01);
                rot4(Q100, Q110, e10); rot4(Q101, Q111, e11);
            }
            {   // target PA-2
                float4 e00 = dec4(pc0), e01 = dec4(pc1), e10 = dec4(pc2), e11 = dec4(pc3);
                rot4(Q000, Q001, e00); rot4(Q010, Q011, e01);
                rot4(Q100, Q101, e10); rot4(Q110, Q111, e11);
            }
        } else {
            float4 eA = make_float4(cA, sA, cA, sA);
            rot4(Q000, Q100, eA); rot4(Q001, Q101, eA);
            rot4(Q010, Q110, eA); rot4(Q011, Q111, eA);
            float4 eB = make_float4(cB, sB, cB, sB);
            rot4(Q000, Q010, eB); rot4(Q001, Q011, eB);
            rot4(Q100, Q110, eB); rot4(Q101, Q111, eB);
            float4 eC = make_float4(cC, sC, cC, sC);
            rot4(Q000, Q001, eC); rot4(Q010, Q011, eC);
            rot4(Q100, Q101, eC); rot4(Q110, Q111, eC);
        }
        ldsst4(sl, i0, Q000);            ldsst4(sl, i0 + oc, Q001);
        ldsst4(sl, i0 + ob, Q010);       ldsst4(sl, i0 + ob + oc, Q011);
        ldsst4(sl, i0 + oa, Q100);       ldsst4(sl, i0 + oa + oc, Q101);
        ldsst4(sl, i0 + oa + ob, Q110);  ldsst4(sl, i0 + oa + ob + oc, Q111);
    }
}

// Low pass, targets {3,2,1}. Thread owns amps i0..i0+31 (bits 4..0; bit 0
// ancilla, bit 4 spectator). x-mapping rule: amp bit a>target -> x bit a-2,
// a<target -> x bit a-1 (same x for all three targets here).
template <bool NEUR>
__device__ __forceinline__ void pass_lo2(float* l0, float* l1, int t8,
    const float* tA, const float* tB, const float* tC,
    float cA, float sA, float cB, float sB, float cC, float sC)
{
    const int i0 = t8 << 5, x0 = t8 << 3;
    float4 qa0, qa1, qb0, qb1, qc0, qc1;
    if (NEUR) {
        qa0 = LD4(&tA[x0]); qa1 = LD4(&tA[x0 + 4]);
        qb0 = LD4(&tB[x0]); qb1 = LD4(&tB[x0 + 4]);
        qc0 = LD4(&tC[x0]); qc1 = LD4(&tC[x0 + 4]);
    }
#pragma unroll
    for (int s = 0; s < 2; ++s) {
        float* sl = (s == 0) ? l0 : l1;
        float4 Q0 = ldsld4(sl, i0),      Q1 = ldsld4(sl, i0 + 4);
        float4 Q2 = ldsld4(sl, i0 + 8),  Q3 = ldsld4(sl, i0 + 12);
        float4 Q4 = ldsld4(sl, i0 + 16), Q5 = ldsld4(sl, i0 + 20);
        float4 Q6 = ldsld4(sl, i0 + 24), Q7 = ldsld4(sl, i0 + 28);
        if (NEUR) {
            // target 3: pairs (k, k+2)
            rot4(Q0, Q2, dec4(make_float2(qa0.x, qa0.y)));
            rot4(Q1, Q3, dec4(make_float2(qa0.z, qa0.w)));
            rot4(Q4, Q6, dec4(make_float2(qa1.x, qa1.y)));
            rot4(Q5, Q7, dec4(make_float2(qa1.z, qa1.w)));
            // target 2: pairs (k, k+1)
            rot4(Q0, Q1, dec4(make_float2(qb0.x, qb0.y)));
            rot4(Q2, Q3, dec4(make_float2(qb0.z, qb0.w)));
            rot4(Q4, Q5, dec4(make_float2(qb1.x, qb1.y)));
            rot4(Q6, Q7, dec4(make_float2(qb1.z, qb1.w)));
            // target 1: in-quad
            { float2 d = dec(qc0.x); rotq(Q0, d.x, d.y); }
            { float2 d = dec(qc0.y); rotq(Q1, d.x, d.y); }
            { float2 d = dec(qc0.z); rotq(Q2, d.x, d.y); }
            { float2 d = dec(qc0.w); rotq(Q3, d.x, d.y); }
            { float2 d = dec(qc1.x); rotq(Q4, d.x, d.y); }
            { float2 d = dec(qc1.y); rotq(Q5, d.x, d.y); }
            { float2 d = dec(qc1.z); rotq(Q6, d.x, d.y); }
            { float2 d = dec(qc1.w); rotq(Q7, d.x, d.y); }
        } else {
            float4 eA = make_float4(cA, sA, cA, sA);
            rot4(Q0, Q2, eA); rot4(Q1, Q3, eA); rot4(Q4, Q6, eA); rot4(Q5, Q7, eA);
            float4 eB = make_float4(cB, sB, cB, sB);
            rot4(Q0, Q1, eB); rot4(Q2, Q3, eB); rot4(Q4, Q5, eB); rot4(Q6, Q7, eB);
            rotq(Q0, cC, sC); rotq(Q1, cC, sC); rotq(Q2, cC, sC); rotq(Q3, cC, sC);
            rotq(Q4, cC, sC); rotq(Q5, cC, sC); rotq(Q6, cC, sC); rotq(Q7, cC, sC);
        }
        ldsst4(sl, i0, Q0);      ldsst4(sl, i0 + 4, Q1);
        ldsst4(sl, i0 + 8, Q2);  ldsst4(sl, i0 + 12, Q3);
        ldsst4(sl, i0 + 16, Q4); ldsst4(sl, i0 + 20, Q5);
        ldsst4(sl, i0 + 24, Q6); ldsst4(sl, i0 + 28, Q7);
    }
}

__global__ __launch_bounds__(256, 2) void main_kernel(
    const float* __restrict__ batch, const float* __restrict__ w_u,
    const int* __restrict__ inputs, const float* __restrict__ tab,
    float* __restrict__ psi, float* __restrict__ probs)
{
    __shared__ __align__(16) float lds[2][8192];   // 64 KiB: 2 batch slots
    const int t8 = threadIdx.x;
    const int blk = blockIdx.x;
    const int xcd = blk & 7;
    const int vt = (xcd << 3) | ((blk >> 3) & 7);   // table inout value
    const int pair = blk >> 6;                       // 0..15

    if (blk == 0) {   // zero probs for out_kernel atomics
        float4 z = make_float4(0.f, 0.f, 0.f, 0.f);
        *(float4*)&probs[t8 * 8] = z;
        *(float4*)&probs[t8 * 8 + 4] = z;
    }

    int bb[2], uu[2];
#pragma unroll
    for (int s = 0; s < 2; ++s) {
        int b = pair * 2 + s;
        int fb = 0;
#pragma unroll
        for (int i = 0; i < 6; ++i) fb |= (inputs[b * 6 + i] & 1) << (5 - i);
        bb[s] = b; uu[s] = vt ^ fb;
        const float* src = batch + ((size_t)b << 19) + ((size_t)uu[s] << 13);
#pragma unroll
        for (int k = 0; k < 8; ++k) {
            int i4 = (k * 256 + t8) * 4;
            float4 v = ntload4(&src[i4]);
            *(float4*)&lds[s][SW(i4)] = v;
        }
    }
    float* l0 = lds[0];
    float* l1 = lds[1];

    const float* tb = tab + (vt << 11);
#define TN(j) (tb + (size_t)(j) * 131072)
#define BAR __syncthreads()
    BAR;
    // ---- input layer (neurons 0..11, target bit 12-j) ----
    pass_hi2<12, true>(l0, l1, t8, TN(0), TN(1), TN(2), 0,0,0,0,0,0);  BAR;
    pass_hi2<9,  true>(l0, l1, t8, TN(3), TN(4), TN(5), 0,0,0,0,0,0);  BAR;
    pass_hi2<6,  true>(l0, l1, t8, TN(6), TN(7), TN(8), 0,0,0,0,0,0);  BAR;
    pass_lo2<true>(l0, l1, t8, TN(9), TN(10), TN(11), 0,0,0,0,0,0);    BAR;

#pragma unroll 1
    for (int st2 = 0; st2 < 3; ++st2) {
        const float* wu = w_u + st2 * 12;
        float c0, s0, c1, s1, c2, s2;
        sincosf(wu[0], &s0, &c0); sincosf(wu[1], &s1, &c1); sincosf(wu[2], &s2, &c2);
        pass_hi2<12, false>(l0, l1, t8, 0,0,0, c0,s0, c1,s1, c2,s2);   BAR;
        sincosf(wu[3], &s0, &c0); sincosf(wu[4], &s1, &c1); sincosf(wu[5], &s2, &c2);
        pass_hi2<9, false>(l0, l1, t8, 0,0,0, c0,s0, c1,s1, c2,s2);    BAR;
        sincosf(wu[6], &s0, &c0); sincosf(wu[7], &s1, &c1); sincosf(wu[8], &s2, &c2);
        pass_hi2<6, false>(l0, l1, t8, 0,0,0, c0,s0, c1,s1, c2,s2);    BAR;
        sincosf(wu[9], &s0, &c0); sincosf(wu[10], &s1, &c1); sincosf(wu[11], &s2, &c2);
        pass_lo2<false>(l0, l1, t8, 0,0,0, c0,s0, c1,s1, c2,s2);       BAR;

        const int nb = 12 + st2 * 12;
        pass_hi2<12, true>(l0, l1, t8, TN(nb+0), TN(nb+1), TN(nb+2), 0,0,0,0,0,0); BAR;
        pass_hi2<9,  true>(l0, l1, t8, TN(nb+3), TN(nb+4), TN(nb+5), 0,0,0,0,0,0); BAR;
        pass_hi2<6,  true>(l0, l1, t8, TN(nb+6), TN(nb+7), TN(nb+8), 0,0,0,0,0,0); BAR;
        pass_lo2<true>(l0, l1, t8, TN(nb+9), TN(nb+10), TN(nb+11), 0,0,0,0,0,0);   BAR;
    }
#undef TN
#undef BAR

#pragma unroll
    for (int s = 0; s < 2; ++s) {
        float* dst = psi + ((size_t)bb[s] << 19) + ((size_t)uu[s] << 13);
#pragma unroll
        for (int k = 0; k < 8; ++k) {
            int i4 = (k * 256 + t8) * 4;
            float4 v = *(const float4*)&lds[s][SW(i4)];
            ntstore4(&dst[i4], v);
        }
    }
}

// ============================ K3: output layer + probs ============================
__global__ __launch_bounds__(256, 2) void out_kernel(
    const float* __restrict__ tab, float* __restrict__ psi,
    float* __restrict__ probs)
{
    __shared__ float ts[16384];   // 64 KiB transpose buffer
    const int tid = threadIdx.x;
    const int b = blockIdx.x >> 5;
    const int col = ((blockIdx.x & 31) << 8) | tid;
    float* base = psi + ((size_t)b << 19) + col;
    float a[64];
#pragma unroll
    for (int k = 0; k < 64; ++k)
        a[k] = __builtin_nontemporal_load(&base[(size_t)k << 13]);
    const int w12 = col >> 1;
#pragma unroll
    for (int j = 0; j < 6; ++j) {
        const float* tj = tab + (size_t)(48 + j) * 131072 + w12;
        const int q = 5 - j;
#pragma unroll
        for (int m = 0; m < 32; ++m) {
            int k0 = ((m >> q) << (q + 1)) | (m & ((1 << q) - 1));
            int k1 = k0 | (1 << q);
            float2 e = dec(tj[(size_t)m << 12]);
            float a0 = a[k0], a1 = a[k1];
            a[k0] = e.x * a0 - e.y * a1;
            a[k1] = e.y * a0 + e.x * a1;
        }
    }
#pragma unroll
    for (int k = 0; k < 64; ++k)
        __builtin_nontemporal_store(a[k], &base[(size_t)k << 13]);

    // ---- probs reduction: ts[r*64 + (k ^ (r&63))] = a_r[k]^2 ----
    const int jx = tid & 63;
#pragma unroll
    for (int k = 0; k < 64; ++k) ts[tid * 64 + (k ^ jx)] = a[k] * a[k];
    __syncthreads();
    const int k = tid & 63, seg = tid >> 6;
    float p = 0.f;
#pragma unroll
    for (int j = 0; j < 64; ++j) p += ts[(seg * 64 + j) * 64 + (k ^ j)];
    atomicAdd(&probs[b * 64 + k], p);
}

// ============================ launch ============================
extern "C" void kernel_launch(void* const* d_in, const int* in_sizes, int n_in,
                              void* d_out, int out_size, void* d_ws, size_t ws_size,
                              hipStream_t stream)
{
    const float* batch  = (const float*)d_in[0];
    const float* w_in1  = (const float*)d_in[1];
    const float* w_in2  = (const float*)d_in[2];
    const float* w_u    = (const float*)d_in[3];
    const float* w_k1   = (const float*)d_in[4];
    const float* w_k2   = (const float*)d_in[5];
    const float* w_out1 = (const float*)d_in[6];
    const float* w_out2 = (const float*)d_in[7];
    const int*   inputs = (const int*)d_in[8];
    float* probs = (float*)d_out;
    float* psi   = (float*)d_out + 2048;      // 32*64 probs, then 32*2^19 psi
    float* tab   = (float*)d_ws;              // 54 * 131072 * 4B = 27 MiB packed

    tables_kernel<<<dim3(512, 54), 256, 0, stream>>>(w_in1, w_in2, w_k1, w_k2,
                                                     w_out1, w_out2, tab);
    main_kernel<<<1024, 256, 0, stream>>>(batch, w_u, inputs, tab, psi, probs);
    out_kernel<<<1024, 256, 0, stream>>>(tab, psi, probs);
}